// Round 1
// baseline (293.290 us; speedup 1.0000x reference)
//
#include <hip/hip_runtime.h>
#include <hip/hip_bf16.h>
#include <type_traits>

typedef __bf16 bf16;
typedef __bf16 bf16x2 __attribute__((ext_vector_type(2)));
typedef __bf16 bf16x4 __attribute__((ext_vector_type(4)));
typedef __bf16 bf16x8 __attribute__((ext_vector_type(8)));
typedef float f32x4 __attribute__((ext_vector_type(4)));

#define AS1 __attribute__((address_space(1)))
#define AS3 __attribute__((address_space(3)))

// 0.125 (1/sqrt(64)) * log2(e): folded into Q so attn scores are log2-domain.
#define KAPPA 0.180336880111f

__device__ __forceinline__ void load_lds16(const void* g, void* l) {
  __builtin_amdgcn_global_load_lds((AS1 void*)g, (AS3 void*)l, 16, 0, 0);
}
__device__ __forceinline__ float exp2_fast(float x) {
  return __builtin_amdgcn_exp2f(x);
}

// ---------------------------------------------------------------------------
// All fp32->bf16 conversions in one launch.
// ---------------------------------------------------------------------------
__global__ void f2b_all(const float* __restrict__ x, const float* __restrict__ wq,
                        const float* __restrict__ wk, const float* __restrict__ wv,
                        const float* __restrict__ wo, bf16* __restrict__ xb,
                        bf16* __restrict__ wqkv, bf16* __restrict__ wob) {
  int bid = blockIdx.x;
  const float* src;
  bf16* dst;
  int off;
  if (bid < 8192) { src = x; dst = xb; off = bid; }
  else if (bid < 12288) { src = wq; dst = wqkv; off = bid - 8192; }
  else if (bid < 13312) { src = wk; dst = wqkv + 4194304; off = bid - 12288; }
  else if (bid < 14336) { src = wv; dst = wqkv + 5242880; off = bid - 13312; }
  else { src = wo; dst = wob; off = bid - 14336; }
  int i = (off * 256 + threadIdx.x) * 4;
  float4 v = *(const float4*)(src + i);
  bf16x4 o = {(bf16)v.x, (bf16)v.y, (bf16)v.z, (bf16)v.w};
  *(bf16x4*)(dst + i) = o;
}

// ---------------------------------------------------------------------------
// Fused QKV projection GEMM, 8-phase-style deep-pipelined schedule:
//   256x256 tile, BK=32, 4-slot LDS ring, prefetch distance 3 tiles,
//   counted vmcnt (8 in steady state, never 0 in the main loop),
//   raw s_barrier (no implicit vmcnt drain), setprio(1) around MFMA clusters.
// 8 waves (2M x 4N), per-wave output 128x64 (acc[8][4]).
// LDS rows are 64B (4 x 16B segs), xor-swizzled seg ^= row&3; read-side
// swizzle folds to a per-thread constant because row&3 == ln&3 everywhere.
// Epilogue: bn<8 -> Q+rope*KAPPA (B,32,S,64); bn in {8,9} -> K+rope
// (B,8,S,64); bn in {10,11} -> V^T (B,8,64,S).
// Grid: (12,16) = 192 blocks, 512 thr, 1 block/CU (128 KiB LDS).
// ---------------------------------------------------------------------------
__global__ __launch_bounds__(512, 2) void gemm_qkv(const bf16* __restrict__ A,
                                                   const bf16* __restrict__ Bw,
                                                   const float* __restrict__ fc,
                                                   const float* __restrict__ fs,
                                                   bf16* __restrict__ Qro,
                                                   bf16* __restrict__ Kro,
                                                   bf16* __restrict__ Vt) {
  const int K = 2048;
  __shared__ bf16 As[4][256][32];  // 64 KB ring (4 slots x 16 KB)
  __shared__ bf16 Bs[4][256][32];  // 64 KB ring
  const int t = threadIdx.x;
  const int wave = t >> 6, lane = t & 63, qd = lane >> 4, ln = lane & 15;
  const int wm = (wave >> 2) * 128;  // 0 or 128
  const int wn = (wave & 3) * 64;    // 0,64,128,192
  const int bn = blockIdx.x;         // 0..11 (Q:0-7, K:8-9, V:10-11)
  const int bmrow = blockIdx.y * 256;

  const bf16* Ab = A + (size_t)bmrow * K;
  const bf16* Bb = Bw + (size_t)bn * 256 * K;

  // Stage one 8KB chunk (sub=0/1) of K-tile tk into the ring.
  // LDS dest is linear (wave-uniform base + lane*16); the seg swizzle is
  // applied on the GLOBAL source address (both-sides-or-neither rule).
  auto stage = [&](const bf16* gb, char* lb, int tk, int sub) {
    int e = sub * 512 + t;
    int ro = e >> 2, gs = (e & 3) ^ (ro & 3);
    load_lds16(gb + (size_t)ro * K + tk * 32 + gs * 8,
               lb + (tk & 3) * 16384 + sub * 8192 + wave * 1024);
  };

  // Prologue: stage tiles 0,1,2 (12 loads/wave), land tile 0 (keep 8 in flight).
#pragma unroll
  for (int tt = 0; tt < 3; tt++) {
    stage(Ab, (char*)As, tt, 0);
    stage(Ab, (char*)As, tt, 1);
    stage(Bb, (char*)Bs, tt, 0);
    stage(Bb, (char*)Bs, tt, 1);
  }
  asm volatile("s_waitcnt vmcnt(8)" ::: "memory");
  __builtin_amdgcn_s_barrier();

  f32x4 acc[8][4] = {};
  bf16x8 bfr[4];
  // row&3 == ln&3 for every fragment row -> read-side swizzle is constant.
  const int segoff = (qd ^ (ln & 3)) << 4;

  for (int tk = 0; tk < 64; tk++) {
    const char* Asl = (const char*)As + (tk & 3) * 16384;
    const char* Bsl = (const char*)Bs + (tk & 3) * 16384;

    // ---- phase A: frags for rows wm..wm+63 + all B frags; stage A of tk+3
    bf16x8 af[4];
#pragma unroll
    for (int i = 0; i < 4; i++)
      af[i] = *(const bf16x8*)(Asl + (wm + i * 16 + ln) * 64 + segoff);
#pragma unroll
    for (int j = 0; j < 4; j++)
      bfr[j] = *(const bf16x8*)(Bsl + (wn + j * 16 + ln) * 64 + segoff);
    if (tk + 3 < 64) {
      stage(Ab, (char*)As, tk + 3, 0);
      stage(Ab, (char*)As, tk + 3, 1);
    }
    __builtin_amdgcn_s_barrier();
    asm volatile("s_waitcnt lgkmcnt(0)" ::: "memory");
    __builtin_amdgcn_sched_barrier(0);
    __builtin_amdgcn_s_setprio(1);
#pragma unroll
    for (int i = 0; i < 4; i++)
#pragma unroll
      for (int j = 0; j < 4; j++)
        acc[i][j] = __builtin_amdgcn_mfma_f32_16x16x32_bf16(af[i], bfr[j],
                                                            acc[i][j], 0, 0, 0);
    __builtin_amdgcn_s_setprio(0);
    __builtin_amdgcn_s_barrier();

    // ---- phase B: frags for rows wm+64..wm+127 (reuse bfr); stage B of tk+3
#pragma unroll
    for (int i = 0; i < 4; i++)
      af[i] = *(const bf16x8*)(Asl + (wm + 64 + i * 16 + ln) * 64 + segoff);
    if (tk + 3 < 64) {
      stage(Bb, (char*)Bs, tk + 3, 0);
      stage(Bb, (char*)Bs, tk + 3, 1);
    }
    // Counted wait: retire tile tk+1 (needed next iter); keep tk+2,tk+3 in
    // flight. Tail: tk=61 keeps only tile 63 (vmcnt 4), tk>=62 drains.
    if (tk < 61) asm volatile("s_waitcnt vmcnt(8)" ::: "memory");
    else if (tk == 61) asm volatile("s_waitcnt vmcnt(4)" ::: "memory");
    else asm volatile("s_waitcnt vmcnt(0)" ::: "memory");
    __builtin_amdgcn_s_barrier();
    asm volatile("s_waitcnt lgkmcnt(0)" ::: "memory");
    __builtin_amdgcn_sched_barrier(0);
    __builtin_amdgcn_s_setprio(1);
#pragma unroll
    for (int i = 0; i < 4; i++)
#pragma unroll
      for (int j = 0; j < 4; j++)
        acc[4 + i][j] = __builtin_amdgcn_mfma_f32_16x16x32_bf16(
            af[i], bfr[j], acc[4 + i][j], 0, 0, 0);
    __builtin_amdgcn_s_setprio(0);
    __builtin_amdgcn_s_barrier();
  }

  // ---- epilogue ----
  const int b = bmrow >> 11;
  const int sb = (bmrow & 2047) + wm;
  const bool odd = ln & 1;

  if (bn < 10) {  // Q or K: rope, head-major output
    const bool isQ = bn < 8;
    const float kap = isQ ? KAPPA : 1.0f;
    const int h = (isQ ? bn : bn - 8) * 4 + (wave & 3);
    bf16* dst = isQ ? (Qro + (size_t)(b * 32 + h) * 2048 * 64)
                    : (Kro + (size_t)(b * 8 + h) * 2048 * 64);
#pragma unroll
    for (int i = 0; i < 8; i++) {
#pragma unroll
      for (int j = 0; j < 4; j++) {
        const int d = j * 16 + ln;
        const int i_f = d >> 1;
#pragma unroll
        for (int r = 0; r < 4; r++) {
          int s = sb + i * 16 + qd * 4 + r;
          float v = acc[i][j][r];
          float p = __shfl_xor(v, 1);
          float cv = fc[s * 32 + i_f] * kap;
          float sv = fs[s * 32 + i_f] * kap;
          float o = odd ? (p * sv + v * cv) : (v * cv - p * sv);
          dst[(size_t)s * 64 + d] = (bf16)o;
        }
      }
    }
  } else {  // V: write transposed (B,8,64,S)
    const int kh = (bn - 10) * 4 + (wave & 3);
#pragma unroll
    for (int i = 0; i < 8; i++)
#pragma unroll
      for (int j = 0; j < 4; j++) {
        const int d = j * 16 + ln;
        int s = sb + i * 16 + qd * 4;
        bf16x4 ov = {(bf16)acc[i][j][0], (bf16)acc[i][j][1],
                     (bf16)acc[i][j][2], (bf16)acc[i][j][3]};
        *(bf16x4*)&Vt[((size_t)(b * 8 + kh) * 64 + d) * 2048 + s] = ov;
      }
  }
}

// ---------------------------------------------------------------------------
// Output projection GEMM, 64x128 tile, BK=64, grid 1024 = 4 blocks/CU.
// ---------------------------------------------------------------------------
template <typename OutT>
__global__ __launch_bounds__(256, 4) void gemm_bt64(const bf16* __restrict__ A,
                                                    const bf16* __restrict__ Bw,
                                                    OutT* __restrict__ C,
                                                    int M, int N, int K) {
  __shared__ bf16 As[64][64];    // 8 KB
  __shared__ bf16 Bs[128][64];   // 16 KB
  const int t = threadIdx.x;
  const int wave = t >> 6, lane = t & 63, qd = lane >> 4, ln = lane & 15;
  const int wm = (wave >> 1) * 32;
  const int wn = (wave & 1) * 64;
  const size_t bm = (size_t)blockIdx.y * 64;
  const size_t bn = (size_t)blockIdx.x * 128;

  const bf16* Ab = A + bm * (size_t)K;
  const bf16* Bb = Bw + bn * (size_t)K;

  f32x4 acc[2][4] = {};

  for (int k0 = 0; k0 < K; k0 += 64) {
#pragma unroll
    for (int i = 0; i < 2; i++) {
      int e = i * 256 + t;
      int ro = e >> 3, gs = (e & 7) ^ (ro & 7);
      load_lds16(Ab + (size_t)ro * K + k0 + gs * 8,
                 (char*)As + i * 4096 + wave * 1024);
    }
#pragma unroll
    for (int i = 0; i < 4; i++) {
      int e = i * 256 + t;
      int ro = e >> 3, gs = (e & 7) ^ (ro & 7);
      load_lds16(Bb + (size_t)ro * K + k0 + gs * 8,
                 (char*)Bs + i * 4096 + wave * 1024);
    }
    __syncthreads();

#pragma unroll
    for (int kk = 0; kk < 2; kk++) {
      bf16x8 af[2], bfr[4];
#pragma unroll
      for (int i = 0; i < 2; i++) {
        int row = wm + i * 16 + ln;
        int ps = (kk * 4 + qd) ^ (row & 7);
        af[i] = *(const bf16x8*)((const char*)As + row * 128 + ps * 16);
      }
#pragma unroll
      for (int j = 0; j < 4; j++) {
        int row = wn + j * 16 + ln;
        int ps = (kk * 4 + qd) ^ (row & 7);
        bfr[j] = *(const bf16x8*)((const char*)Bs + row * 128 + ps * 16);
      }
#pragma unroll
      for (int i = 0; i < 2; i++)
#pragma unroll
        for (int j = 0; j < 4; j++)
          acc[i][j] = __builtin_amdgcn_mfma_f32_16x16x32_bf16(af[i], bfr[j],
                                                              acc[i][j], 0, 0, 0);
    }
    __syncthreads();
  }

#pragma unroll
  for (int i = 0; i < 2; i++)
#pragma unroll
    for (int j = 0; j < 4; j++)
#pragma unroll
      for (int r = 0; r < 4; r++) {
        size_t row = bm + wm + i * 16 + qd * 4 + r;
        size_t col = bn + wn + j * 16 + ln;
        C[row * N + col] = (OutT)acc[i][j][r];
      }
}

// ---------------------------------------------------------------------------
// Flash attention, S^T formulation, causal, log2-domain FIXED-POINT softmax:
// p = 2^(s-16) (scores bounded, shift-invariant). No running max/alpha;
// l-reduction deferred to epilogue.
// Q:(B,32,S,64)  K:(B,8,S,64)  Vt:(B,8,64,S)  ->  O:(B,S,32,64)
// ---------------------------------------------------------------------------
__global__ __launch_bounds__(256, 3) void attn_fwd(const bf16* __restrict__ Q,
                                                   const bf16* __restrict__ Kg,
                                                   const bf16* __restrict__ Vg,
                                                   bf16* __restrict__ O) {
  __shared__ bf16 Qs[128][64];
  __shared__ bf16 Ks[64][64];
  __shared__ bf16 Vs[64][64];   // [d][k]
  __shared__ bf16 Ps[128][64];  // [q][k], swizzled
  const int t = threadIdx.x;
  const int wave = t >> 6, lane = t & 63, qd = lane >> 4, ln = lane & 15;
  const int bid = blockIdx.x;
  const int qt = 15 - (bid >> 6);  // longest blocks dispatch first
  const int bh = bid & 63;
  const int b = bh >> 5, h = bh & 31, kh = h >> 2;
  const bf16* Qb = Q + ((size_t)(b * 32 + h) * 2048 + qt * 128) * 64;  // contiguous
  const bf16* Kb = Kg + (size_t)(b * 8 + kh) * 2048 * 64;              // contiguous
  const bf16* Vb = Vg + (size_t)(b * 8 + kh) * 64 * 2048;              // row stride 2048
  char* PsB = (char*)Ps;

#pragma unroll
  for (int i = 0; i < 4; i++) {
    int e = i * 256 + t;
    int row = e >> 3, sg = (e & 7) ^ (row & 7);
    load_lds16(Qb + (size_t)row * 64 + sg * 8, (char*)Qs + i * 4096 + wave * 1024);
  }

  f32x4 o_acc[4][2] = {};
  float l_st[2] = {0.f, 0.f};
  const int q0 = qt * 128 + wave * 32;
  const int nkb = 2 * qt + 2;

  for (int kb = 0; kb < nkb; kb++) {
    __syncthreads();
#pragma unroll
    for (int i = 0; i < 2; i++) {
      int e = i * 256 + t;
      int row = e >> 3, sg = (e & 7) ^ (row & 7);
      load_lds16(Kb + (size_t)(kb * 64 + row) * 64 + sg * 8,
                 (char*)Ks + i * 4096 + wave * 1024);
      load_lds16(Vb + (size_t)row * 2048 + kb * 64 + sg * 8,
                 (char*)Vs + i * 4096 + wave * 1024);
    }
    __syncthreads();

    // S^T = K*Q^T
    f32x4 s_acc[4][2] = {};
#pragma unroll
    for (int kk = 0; kk < 2; kk++) {
      bf16x8 ak[4], bq[2];
#pragma unroll
      for (int j = 0; j < 4; j++) {
        int row = j * 16 + ln;
        int ph = (kk * 4 + qd) ^ (ln & 7);
        ak[j] = *(const bf16x8*)((const char*)Ks + row * 128 + ph * 16);
      }
#pragma unroll
      for (int mi = 0; mi < 2; mi++) {
        int row = wave * 32 + mi * 16 + ln;
        int ph = (kk * 4 + qd) ^ (ln & 7);
        bq[mi] = *(const bf16x8*)((const char*)Qs + row * 128 + ph * 16);
      }
#pragma unroll
      for (int j = 0; j < 4; j++)
#pragma unroll
        for (int mi = 0; mi < 2; mi++)
          s_acc[j][mi] = __builtin_amdgcn_mfma_f32_16x16x32_bf16(
              ak[j], bq[mi], s_acc[j][mi], 0, 0, 0);
    }

    // fixed-point softmax: p = 2^(s-16); masked -> exact 0
    auto smax = [&](auto maskc) {
      constexpr bool MASK = decltype(maskc)::value;
#pragma unroll
      for (int mi = 0; mi < 2; mi++) {
        const int qv = q0 + mi * 16 + ln;
        const int prow = wave * 32 + mi * 16 + ln;
        float rs = 0.f;
#pragma unroll
        for (int j = 0; j < 4; j++) {
          bf16x4 pk;
#pragma unroll
          for (int r = 0; r < 4; r++) {
            float s = s_acc[j][mi][r];
            if (MASK) {
              int k_glob = kb * 64 + j * 16 + qd * 4 + r;
              if (k_glob > qv) s = -1e5f;
            }
            float pv = exp2_fast(s - 16.f);
            rs += pv;
            pk[r] = (bf16)pv;
          }
          int ps = (j * 2 + (qd >> 1)) ^ (ln & 7);
          *(bf16x4*)(PsB + prow * 128 + ps * 16 + (qd & 1) * 8) = pk;
        }
        l_st[mi] += rs;
      }
    };
    if (kb * 64 + 63 > q0) smax(std::true_type{});
    else smax(std::false_type{});

    // O^T += V^T * P^T  (Ps wave-private; lgkmcnt orders write->read)
#pragma unroll
    for (int kk = 0; kk < 2; kk++) {
      bf16x8 av[4], bp[2];
#pragma unroll
      for (int dj = 0; dj < 4; dj++) {
        int row = dj * 16 + ln;
        int ph = (kk * 4 + qd) ^ (ln & 7);
        av[dj] = *(const bf16x8*)((const char*)Vs + row * 128 + ph * 16);
      }
#pragma unroll
      for (int mi = 0; mi < 2; mi++) {
        int prow = wave * 32 + mi * 16 + ln;
        int ph = (kk * 4 + qd) ^ (ln & 7);
        bp[mi] = *(const bf16x8*)(PsB + prow * 128 + ph * 16);
      }
#pragma unroll
      for (int dj = 0; dj < 4; dj++)
#pragma unroll
        for (int mi = 0; mi < 2; mi++)
          o_acc[dj][mi] = __builtin_amdgcn_mfma_f32_16x16x32_bf16(
              av[dj], bp[mi], o_acc[dj][mi], 0, 0, 0);
    }
  }

  // epilogue: reduce l across quads (each quad summed a disjoint k-subset)
#pragma unroll
  for (int mi = 0; mi < 2; mi++) {
    float lt = l_st[mi];
    lt += __shfl_xor(lt, 16);
    lt += __shfl_xor(lt, 32);
    float inv = 1.f / lt;
    int q_idx = qt * 128 + wave * 32 + mi * 16 + ln;
#pragma unroll
    for (int dj = 0; dj < 4; dj++) {
      bf16x4 ov;
#pragma unroll
      for (int r = 0; r < 4; r++) ov[r] = (bf16)(o_acc[dj][mi][r] * inv);
      *(bf16x4*)&O[((size_t)(b * 2048 + q_idx) * 32 + h) * 64 + dj * 16 + qd * 4] = ov;
    }
  }
}

// ---------------------------------------------------------------------------
extern "C" void kernel_launch(void* const* d_in, const int* in_sizes, int n_in,
                              void* d_out, int out_size, void* d_ws,
                              size_t ws_size, hipStream_t stream) {
  const float* x = (const float*)d_in[0];
  const float* fc = (const float*)d_in[1];
  const float* fs = (const float*)d_in[2];
  const float* wq = (const float*)d_in[3];
  const float* wk = (const float*)d_in[4];
  const float* wv = (const float*)d_in[5];
  const float* wo = (const float*)d_in[6];
  float* out = (float*)d_out;

  char* ws = (char*)d_ws;
  const size_t MB = (size_t)1 << 20;
  bf16* xb   = (bf16*)(ws + 0 * MB);   // 16 MB (4096,2048)
  bf16* wqkv = (bf16*)(ws + 16 * MB);  // 12 MB (3072,2048)
  bf16* wob  = (bf16*)(ws + 28 * MB);  // 8 MB
  bf16* Qro  = (bf16*)(ws + 36 * MB);  // 16 MB (B,32,S,64), roped*KAPPA
  bf16* Kro  = (bf16*)(ws + 52 * MB);  // 4 MB  (B,8,S,64), roped
  bf16* Vt   = (bf16*)(ws + 56 * MB);  // 4 MB  (B,8,64,S)
  bf16* Oa   = (bf16*)(ws + 60 * MB);  // 16 MB (B,S,32,64)

  dim3 blk(256);
  f2b_all<<<18432, blk, 0, stream>>>(x, wq, wk, wv, wo, xb, wqkv, wob);
  gemm_qkv<<<dim3(12, 16), dim3(512), 0, stream>>>(xb, wqkv, fc, fs, Qro, Kro, Vt);
  attn_fwd<<<1024, blk, 0, stream>>>(Qro, Kro, Vt, Oa);
  gemm_bt64<float><<<dim3(16, 64), blk, 0, stream>>>(Oa, wob, out, 4096, 2048, 2048);
}

// Round 2
// 273.759 us; speedup vs baseline: 1.0713x; 1.0713x over previous
//
#include <hip/hip_runtime.h>
#include <hip/hip_bf16.h>
#include <type_traits>

typedef __bf16 bf16;
typedef __bf16 bf16x2 __attribute__((ext_vector_type(2)));
typedef __bf16 bf16x4 __attribute__((ext_vector_type(4)));
typedef __bf16 bf16x8 __attribute__((ext_vector_type(8)));
typedef float f32x4 __attribute__((ext_vector_type(4)));

#define AS1 __attribute__((address_space(1)))
#define AS3 __attribute__((address_space(3)))

// 0.125 (1/sqrt(64)) * log2(e): folded into Q so attn scores are log2-domain.
#define KAPPA 0.180336880111f

__device__ __forceinline__ void load_lds16(const void* g, void* l) {
  __builtin_amdgcn_global_load_lds((AS1 void*)g, (AS3 void*)l, 16, 0, 0);
}
__device__ __forceinline__ float exp2_fast(float x) {
  return __builtin_amdgcn_exp2f(x);
}

// ---------------------------------------------------------------------------
// All fp32->bf16 conversions in one launch.
// ---------------------------------------------------------------------------
__global__ void f2b_all(const float* __restrict__ x, const float* __restrict__ wq,
                        const float* __restrict__ wk, const float* __restrict__ wv,
                        const float* __restrict__ wo, bf16* __restrict__ xb,
                        bf16* __restrict__ wqkv, bf16* __restrict__ wob) {
  int bid = blockIdx.x;
  const float* src;
  bf16* dst;
  int off;
  if (bid < 8192) { src = x; dst = xb; off = bid; }
  else if (bid < 12288) { src = wq; dst = wqkv; off = bid - 8192; }
  else if (bid < 13312) { src = wk; dst = wqkv + 4194304; off = bid - 12288; }
  else if (bid < 14336) { src = wv; dst = wqkv + 5242880; off = bid - 13312; }
  else { src = wo; dst = wob; off = bid - 14336; }
  int i = (off * 256 + threadIdx.x) * 4;
  float4 v = *(const float4*)(src + i);
  bf16x4 o = {(bf16)v.x, (bf16)v.y, (bf16)v.z, (bf16)v.w};
  *(bf16x4*)(dst + i) = o;
}

// ---------------------------------------------------------------------------
// Fused QKV projection GEMM, deep-pipelined schedule:
//   256x192 tile (grid 16x16 = 256 blocks -> every CU busy, one full round),
//   BK=32, 4-slot LDS ring, prefetch distance 3 tiles,
//   counted vmcnt (never 0 in the main loop; wave-dependent since waves 0-3
//   carry the extra half-stage of the 192-row B tile),
//   raw s_barrier + setprio(1) around MFMA clusters.
// 8 waves (2M x 4N), per-wave output 128x48 (acc[8][3]).
// LDS rows are 64B (4 x 16B segs), xor-swizzled seg ^= (row>>1)&3.
//   Bank check (8-lane ds_read_b128 group, rows base..base+7, base%16==0):
//   slot16B = 4*(row&1) + (qd ^ ((row>>1)&3)) -> bijection onto 0..7 ->
//   conflict-free. (Round-1's seg^=(row&3) double-used row bit0 -> 2-way.)
//   Read-side seg offset folds to per-thread constant (qd ^ ((ln>>1)&3)).
// Epilogue: 192 cols span 3 heads; head type is wave-uniform per j-fragment
//   (cols 16-aligned, heads 64-aligned). hg<32 -> Q+rope*KAPPA (B,32,S,64);
//   hg<40 -> K+rope (B,8,S,64); else V^T (B,8,64,S).
// ---------------------------------------------------------------------------
__global__ __launch_bounds__(512, 2) void gemm_qkv(const bf16* __restrict__ A,
                                                   const bf16* __restrict__ Bw,
                                                   const float* __restrict__ fc,
                                                   const float* __restrict__ fs,
                                                   bf16* __restrict__ Qro,
                                                   bf16* __restrict__ Kro,
                                                   bf16* __restrict__ Vt) {
  const int K = 2048;
  __shared__ bf16 As[4][256][32];  // 64 KB ring (4 slots x 16 KB)
  __shared__ bf16 Bs[4][192][32];  // 48 KB ring (4 slots x 12 KB)
  const int t = threadIdx.x;
  const int wave = t >> 6, lane = t & 63, qd = lane >> 4, ln = lane & 15;
  const int wm = (wave >> 2) * 128;  // 0 or 128
  const int wn = (wave & 3) * 48;    // 0,48,96,144
  const int bn = blockIdx.x;         // 0..15
  const int bmrow = blockIdx.y * 256;

  const bf16* Ab = A + (size_t)bmrow * K;
  const bf16* Bb = Bw + (size_t)bn * 192 * K;

  // A tile: 256 rows x 4 segs = 1024 e's = 2 full 512-thread subs.
  auto stageA = [&](int tk, int sub) {
    int e = sub * 512 + t;
    int ro = e >> 2, gs = (e & 3) ^ ((ro >> 1) & 3);
    load_lds16(Ab + (size_t)ro * K + tk * 32 + gs * 8,
               (char*)As + (tk & 3) * 16384 + sub * 8192 + wave * 1024);
  };
  // B tile: 192 rows x 4 segs = 768 e's = 1 full sub + 1 half sub (waves 0-3).
  auto stageB = [&](int tk, int sub) {
    if (sub == 0 || t < 256) {
      int e = sub * 512 + t;
      int ro = e >> 2, gs = (e & 3) ^ ((ro >> 1) & 3);
      load_lds16(Bb + (size_t)ro * K + tk * 32 + gs * 8,
                 (char*)Bs + (tk & 3) * 12288 + sub * 8192 + wave * 1024);
    }
  };

  // Prologue: stage tiles 0,1,2. Loads/tile: waves 0-3: 4, waves 4-7: 3.
#pragma unroll
  for (int tt = 0; tt < 3; tt++) {
    stageA(tt, 0);
    stageA(tt, 1);
    stageB(tt, 0);
    stageB(tt, 1);
  }
  // Land tile 0, keep tiles 1,2 in flight.
  if (wave < 4) asm volatile("s_waitcnt vmcnt(8)" ::: "memory");
  else         asm volatile("s_waitcnt vmcnt(6)" ::: "memory");
  __builtin_amdgcn_s_barrier();

  f32x4 acc[8][3] = {};
  bf16x8 bfr[3];
  // (row>>1)&3 == (ln>>1)&3 for every fragment row (bases are 16-multiples).
  const int segoff = (qd ^ ((ln >> 1) & 3)) << 4;

  for (int tk = 0; tk < 64; tk++) {
    const char* Asl = (const char*)As + (tk & 3) * 16384;
    const char* Bsl = (const char*)Bs + (tk & 3) * 12288;

    // ---- phase A: A rows wm..wm+63 + all B frags; stage A-subs of tk+3
    bf16x8 af[4];
#pragma unroll
    for (int i = 0; i < 4; i++)
      af[i] = *(const bf16x8*)(Asl + (wm + i * 16 + ln) * 64 + segoff);
#pragma unroll
    for (int j = 0; j < 3; j++)
      bfr[j] = *(const bf16x8*)(Bsl + (wn + j * 16 + ln) * 64 + segoff);
    if (tk + 3 < 64) {
      stageA(tk + 3, 0);
      stageA(tk + 3, 1);
    }
    __builtin_amdgcn_s_barrier();
    asm volatile("s_waitcnt lgkmcnt(0)" ::: "memory");
    __builtin_amdgcn_sched_barrier(0);
    __builtin_amdgcn_s_setprio(1);
#pragma unroll
    for (int i = 0; i < 4; i++)
#pragma unroll
      for (int j = 0; j < 3; j++)
        acc[i][j] = __builtin_amdgcn_mfma_f32_16x16x32_bf16(af[i], bfr[j],
                                                            acc[i][j], 0, 0, 0);
    __builtin_amdgcn_s_setprio(0);
    __builtin_amdgcn_s_barrier();

    // ---- phase B: A rows wm+64..wm+127 (reuse bfr); stage B-subs of tk+3
#pragma unroll
    for (int i = 0; i < 4; i++)
      af[i] = *(const bf16x8*)(Asl + (wm + 64 + i * 16 + ln) * 64 + segoff);
    if (tk + 3 < 64) {
      stageB(tk + 3, 0);
      stageB(tk + 3, 1);
    }
    // Counted wait: tile tk+1 must land (read next iter); keep tk+2,tk+3 in
    // flight. Per-tile loads differ by wave (4 vs 3) -> wave-dependent count.
    if (tk < 61) {
      if (wave < 4) asm volatile("s_waitcnt vmcnt(8)" ::: "memory");
      else         asm volatile("s_waitcnt vmcnt(6)" ::: "memory");
    } else if (tk == 61) {
      if (wave < 4) asm volatile("s_waitcnt vmcnt(4)" ::: "memory");
      else         asm volatile("s_waitcnt vmcnt(3)" ::: "memory");
    } else {
      asm volatile("s_waitcnt vmcnt(0)" ::: "memory");
    }
    __builtin_amdgcn_s_barrier();
    asm volatile("s_waitcnt lgkmcnt(0)" ::: "memory");
    __builtin_amdgcn_sched_barrier(0);
    __builtin_amdgcn_s_setprio(1);
#pragma unroll
    for (int i = 0; i < 4; i++)
#pragma unroll
      for (int j = 0; j < 3; j++)
        acc[4 + i][j] = __builtin_amdgcn_mfma_f32_16x16x32_bf16(
            af[i], bfr[j], acc[4 + i][j], 0, 0, 0);
    __builtin_amdgcn_s_setprio(0);
    __builtin_amdgcn_s_barrier();
  }

  // ---- epilogue ----
  const int b = bmrow >> 11;
  const int sb = (bmrow & 2047) + wm;
  const bool odd = ln & 1;

#pragma unroll
  for (int j = 0; j < 3; j++) {
    const int cbase = bn * 192 + wn + j * 16;  // wave-uniform
    const int hg = cbase >> 6;                 // 0..47: Q 0-31, K 32-39, V 40-47
    const int d = (cbase & 63) + ln;
    if (hg < 40) {  // Q or K: rope, head-major output
      const bool isQ = hg < 32;
      const float kap = isQ ? KAPPA : 1.0f;
      bf16* dst = isQ ? (Qro + (size_t)(b * 32 + hg) * 2048 * 64)
                      : (Kro + (size_t)(b * 8 + (hg - 32)) * 2048 * 64);
      const int i_f = d >> 1;
#pragma unroll
      for (int i = 0; i < 8; i++) {
#pragma unroll
        for (int r = 0; r < 4; r++) {
          int s = sb + i * 16 + qd * 4 + r;
          float v = acc[i][j][r];
          float p = __shfl_xor(v, 1);
          float cv = fc[s * 32 + i_f] * kap;
          float sv = fs[s * 32 + i_f] * kap;
          float o = odd ? (p * sv + v * cv) : (v * cv - p * sv);
          dst[(size_t)s * 64 + d] = (bf16)o;
        }
      }
    } else {  // V: write transposed (B,8,64,S)
      const int kh = hg - 40;
#pragma unroll
      for (int i = 0; i < 8; i++) {
        int s = sb + i * 16 + qd * 4;
        bf16x4 ov = {(bf16)acc[i][j][0], (bf16)acc[i][j][1],
                     (bf16)acc[i][j][2], (bf16)acc[i][j][3]};
        *(bf16x4*)&Vt[((size_t)(b * 8 + kh) * 64 + d) * 2048 + s] = ov;
      }
    }
  }
}

// ---------------------------------------------------------------------------
// Output projection GEMM, 64x128 tile, BK=64, grid 1024 = 4 blocks/CU.
// ---------------------------------------------------------------------------
template <typename OutT>
__global__ __launch_bounds__(256, 4) void gemm_bt64(const bf16* __restrict__ A,
                                                    const bf16* __restrict__ Bw,
                                                    OutT* __restrict__ C,
                                                    int M, int N, int K) {
  __shared__ bf16 As[64][64];    // 8 KB
  __shared__ bf16 Bs[128][64];   // 16 KB
  const int t = threadIdx.x;
  const int wave = t >> 6, lane = t & 63, qd = lane >> 4, ln = lane & 15;
  const int wm = (wave >> 1) * 32;
  const int wn = (wave & 1) * 64;
  const size_t bm = (size_t)blockIdx.y * 64;
  const size_t bn = (size_t)blockIdx.x * 128;

  const bf16* Ab = A + bm * (size_t)K;
  const bf16* Bb = Bw + bn * (size_t)K;

  f32x4 acc[2][4] = {};

  for (int k0 = 0; k0 < K; k0 += 64) {
#pragma unroll
    for (int i = 0; i < 2; i++) {
      int e = i * 256 + t;
      int ro = e >> 3, gs = (e & 7) ^ (ro & 7);
      load_lds16(Ab + (size_t)ro * K + k0 + gs * 8,
                 (char*)As + i * 4096 + wave * 1024);
    }
#pragma unroll
    for (int i = 0; i < 4; i++) {
      int e = i * 256 + t;
      int ro = e >> 3, gs = (e & 7) ^ (ro & 7);
      load_lds16(Bb + (size_t)ro * K + k0 + gs * 8,
                 (char*)Bs + i * 4096 + wave * 1024);
    }
    __syncthreads();

#pragma unroll
    for (int kk = 0; kk < 2; kk++) {
      bf16x8 af[2], bfr[4];
#pragma unroll
      for (int i = 0; i < 2; i++) {
        int row = wm + i * 16 + ln;
        int ps = (kk * 4 + qd) ^ (row & 7);
        af[i] = *(const bf16x8*)((const char*)As + row * 128 + ps * 16);
      }
#pragma unroll
      for (int j = 0; j < 4; j++) {
        int row = wn + j * 16 + ln;
        int ps = (kk * 4 + qd) ^ (row & 7);
        bfr[j] = *(const bf16x8*)((const char*)Bs + row * 128 + ps * 16);
      }
#pragma unroll
      for (int i = 0; i < 2; i++)
#pragma unroll
        for (int j = 0; j < 4; j++)
          acc[i][j] = __builtin_amdgcn_mfma_f32_16x16x32_bf16(af[i], bfr[j],
                                                              acc[i][j], 0, 0, 0);
    }
    __syncthreads();
  }

#pragma unroll
  for (int i = 0; i < 2; i++)
#pragma unroll
    for (int j = 0; j < 4; j++)
#pragma unroll
      for (int r = 0; r < 4; r++) {
        size_t row = bm + wm + i * 16 + qd * 4 + r;
        size_t col = bn + wn + j * 16 + ln;
        C[row * N + col] = (OutT)acc[i][j][r];
      }
}

// ---------------------------------------------------------------------------
// Flash attention, S^T formulation, causal, log2-domain FIXED-POINT softmax:
// p = 2^(s-16) (scores bounded, shift-invariant). No running max/alpha;
// l-reduction deferred to epilogue.
// Q:(B,32,S,64)  K:(B,8,S,64)  Vt:(B,8,64,S)  ->  O:(B,S,32,64)
// ---------------------------------------------------------------------------
__global__ __launch_bounds__(256, 3) void attn_fwd(const bf16* __restrict__ Q,
                                                   const bf16* __restrict__ Kg,
                                                   const bf16* __restrict__ Vg,
                                                   bf16* __restrict__ O) {
  __shared__ bf16 Qs[128][64];
  __shared__ bf16 Ks[64][64];
  __shared__ bf16 Vs[64][64];   // [d][k]
  __shared__ bf16 Ps[128][64];  // [q][k], swizzled
  const int t = threadIdx.x;
  const int wave = t >> 6, lane = t & 63, qd = lane >> 4, ln = lane & 15;
  const int bid = blockIdx.x;
  const int qt = 15 - (bid >> 6);  // longest blocks dispatch first
  const int bh = bid & 63;
  const int b = bh >> 5, h = bh & 31, kh = h >> 2;
  const bf16* Qb = Q + ((size_t)(b * 32 + h) * 2048 + qt * 128) * 64;  // contiguous
  const bf16* Kb = Kg + (size_t)(b * 8 + kh) * 2048 * 64;              // contiguous
  const bf16* Vb = Vg + (size_t)(b * 8 + kh) * 64 * 2048;              // row stride 2048
  char* PsB = (char*)Ps;

#pragma unroll
  for (int i = 0; i < 4; i++) {
    int e = i * 256 + t;
    int row = e >> 3, sg = (e & 7) ^ (row & 7);
    load_lds16(Qb + (size_t)row * 64 + sg * 8, (char*)Qs + i * 4096 + wave * 1024);
  }

  f32x4 o_acc[4][2] = {};
  float l_st[2] = {0.f, 0.f};
  const int q0 = qt * 128 + wave * 32;
  const int nkb = 2 * qt + 2;

  for (int kb = 0; kb < nkb; kb++) {
    __syncthreads();
#pragma unroll
    for (int i = 0; i < 2; i++) {
      int e = i * 256 + t;
      int row = e >> 3, sg = (e & 7) ^ (row & 7);
      load_lds16(Kb + (size_t)(kb * 64 + row) * 64 + sg * 8,
                 (char*)Ks + i * 4096 + wave * 1024);
      load_lds16(Vb + (size_t)row * 2048 + kb * 64 + sg * 8,
                 (char*)Vs + i * 4096 + wave * 1024);
    }
    __syncthreads();

    // S^T = K*Q^T
    f32x4 s_acc[4][2] = {};
#pragma unroll
    for (int kk = 0; kk < 2; kk++) {
      bf16x8 ak[4], bq[2];
#pragma unroll
      for (int j = 0; j < 4; j++) {
        int row = j * 16 + ln;
        int ph = (kk * 4 + qd) ^ (ln & 7);
        ak[j] = *(const bf16x8*)((const char*)Ks + row * 128 + ph * 16);
      }
#pragma unroll
      for (int mi = 0; mi < 2; mi++) {
        int row = wave * 32 + mi * 16 + ln;
        int ph = (kk * 4 + qd) ^ (ln & 7);
        bq[mi] = *(const bf16x8*)((const char*)Qs + row * 128 + ph * 16);
      }
#pragma unroll
      for (int j = 0; j < 4; j++)
#pragma unroll
        for (int mi = 0; mi < 2; mi++)
          s_acc[j][mi] = __builtin_amdgcn_mfma_f32_16x16x32_bf16(
              ak[j], bq[mi], s_acc[j][mi], 0, 0, 0);
    }

    // fixed-point softmax: p = 2^(s-16); masked -> exact 0
    auto smax = [&](auto maskc) {
      constexpr bool MASK = decltype(maskc)::value;
#pragma unroll
      for (int mi = 0; mi < 2; mi++) {
        const int qv = q0 + mi * 16 + ln;
        const int prow = wave * 32 + mi * 16 + ln;
        float rs = 0.f;
#pragma unroll
        for (int j = 0; j < 4; j++) {
          bf16x4 pk;
#pragma unroll
          for (int r = 0; r < 4; r++) {
            float s = s_acc[j][mi][r];
            if (MASK) {
              int k_glob = kb * 64 + j * 16 + qd * 4 + r;
              if (k_glob > qv) s = -1e5f;
            }
            float pv = exp2_fast(s - 16.f);
            rs += pv;
            pk[r] = (bf16)pv;
          }
          int ps = (j * 2 + (qd >> 1)) ^ (ln & 7);
          *(bf16x4*)(PsB + prow * 128 + ps * 16 + (qd & 1) * 8) = pk;
        }
        l_st[mi] += rs;
      }
    };
    if (kb * 64 + 63 > q0) smax(std::true_type{});
    else smax(std::false_type{});

    // O^T += V^T * P^T  (Ps wave-private; lgkmcnt orders write->read)
#pragma unroll
    for (int kk = 0; kk < 2; kk++) {
      bf16x8 av[4], bp[2];
#pragma unroll
      for (int dj = 0; dj < 4; dj++) {
        int row = dj * 16 + ln;
        int ph = (kk * 4 + qd) ^ (ln & 7);
        av[dj] = *(const bf16x8*)((const char*)Vs + row * 128 + ph * 16);
      }
#pragma unroll
      for (int mi = 0; mi < 2; mi++) {
        int prow = wave * 32 + mi * 16 + ln;
        int ph = (kk * 4 + qd) ^ (ln & 7);
        bp[mi] = *(const bf16x8*)(PsB + prow * 128 + ph * 16);
      }
#pragma unroll
      for (int dj = 0; dj < 4; dj++)
#pragma unroll
        for (int mi = 0; mi < 2; mi++)
          o_acc[dj][mi] = __builtin_amdgcn_mfma_f32_16x16x32_bf16(
              av[dj], bp[mi], o_acc[dj][mi], 0, 0, 0);
    }
  }

  // epilogue: reduce l across quads (each quad summed a disjoint k-subset)
#pragma unroll
  for (int mi = 0; mi < 2; mi++) {
    float lt = l_st[mi];
    lt += __shfl_xor(lt, 16);
    lt += __shfl_xor(lt, 32);
    float inv = 1.f / lt;
    int q_idx = qt * 128 + wave * 32 + mi * 16 + ln;
#pragma unroll
    for (int dj = 0; dj < 4; dj++) {
      bf16x4 ov;
#pragma unroll
      for (int r = 0; r < 4; r++) ov[r] = (bf16)(o_acc[dj][mi][r] * inv);
      *(bf16x4*)&O[((size_t)(b * 2048 + q_idx) * 32 + h) * 64 + dj * 16 + qd * 4] = ov;
    }
  }
}

// ---------------------------------------------------------------------------
extern "C" void kernel_launch(void* const* d_in, const int* in_sizes, int n_in,
                              void* d_out, int out_size, void* d_ws,
                              size_t ws_size, hipStream_t stream) {
  const float* x = (const float*)d_in[0];
  const float* fc = (const float*)d_in[1];
  const float* fs = (const float*)d_in[2];
  const float* wq = (const float*)d_in[3];
  const float* wk = (const float*)d_in[4];
  const float* wv = (const float*)d_in[5];
  const float* wo = (const float*)d_in[6];
  float* out = (float*)d_out;

  char* ws = (char*)d_ws;
  const size_t MB = (size_t)1 << 20;
  bf16* xb   = (bf16*)(ws + 0 * MB);   // 16 MB (4096,2048)
  bf16* wqkv = (bf16*)(ws + 16 * MB);  // 12 MB (3072,2048)
  bf16* wob  = (bf16*)(ws + 28 * MB);  // 8 MB
  bf16* Qro  = (bf16*)(ws + 36 * MB);  // 16 MB (B,32,S,64), roped*KAPPA
  bf16* Kro  = (bf16*)(ws + 52 * MB);  // 4 MB  (B,8,S,64), roped
  bf16* Vt   = (bf16*)(ws + 56 * MB);  // 4 MB  (B,8,64,S)
  bf16* Oa   = (bf16*)(ws + 60 * MB);  // 16 MB (B,S,32,64)

  dim3 blk(256);
  f2b_all<<<18432, blk, 0, stream>>>(x, wq, wk, wv, wo, xb, wqkv, wob);
  gemm_qkv<<<dim3(16, 16), dim3(512), 0, stream>>>(xb, wqkv, fc, fs, Qro, Kro, Vt);
  attn_fwd<<<1024, blk, 0, stream>>>(Qro, Kro, Vt, Oa);
  gemm_bt64<float><<<dim3(16, 64), blk, 0, stream>>>(Oa, wob, out, 4096, 2048, 2048);
}